// Round 11
// baseline (1289.345 us; speedup 1.0000x reference)
//
#include <hip/hip_runtime.h>
#include <math.h>

#define IMG 768
#define WT 16                 // useful wave-tile (16x16)
#define KF 4
#define WI (WT + 2 * KF)      // 24x24 input tile per wave
#define NWT (IMG / WT)        // 48x48 = 2304 wave tiles
#define WPB 9                 // waves per block
#define NT (WPB * 64)         // 576 threads
#define NBLK (NWT * NWT / WPB)  // 256 blocks = exactly 1/CU, 9 waves/CU
#define RES_SCALE 0.1f
#define NITER 64

// GELU: 0.5*x*(1+erf(x/sqrt(2))), erf via Abramowitz-Stegun 7.1.25
// (3-term, |abs err| <= 2.5e-5, validated R10: absmax 4096 vs thr 22609),
// 9 VALU + 2 trans; exp2 underflow gives exact relu saturation at any x.
__device__ __forceinline__ float gelu_fast(float x) {
    float u = x * x;
    float e = __builtin_amdgcn_exp2f(u * -0.72134752044448f);   // exp(-x^2/2)
    float kk = __builtin_amdgcn_rcpf(fmaf(0.332672527f, fabsf(x), 1.0f));
    float p = fmaf(0.7478556f, kk, -0.0958798f);
    p = fmaf(p, kk, 0.3480242f);
    p *= kk;
    float r = fmaf(-p, e, 1.0f);      // erf(|x|/sqrt2) in [0,1]
    float hx = 0.5f * x;
    return fmaf(fabsf(hx), r, hx);    // abs is a free VOP3 modifier
}

// F.interpolate(bilinear, align_corners=False) from the 8x8 seed,
// half-pixel centers; edge handling == index clamp.
__device__ __forceinline__ float bilinear8(const float* __restrict__ seed,
                                           int gy, int gx) {
    float sy = fmaf((float)gy, 0.0104166667f, -0.4947916667f);  // (gy+.5)/96-.5
    float sx = fmaf((float)gx, 0.0104166667f, -0.4947916667f);
    float fy = floorf(sy), fx = floorf(sx);
    float wy = sy - fy, wx = sx - fx;
    int y0 = (int)fy, x0 = (int)fx;
    int y0c = min(max(y0, 0), 7), y1c = min(max(y0 + 1, 0), 7);
    int x0c = min(max(x0, 0), 7), x1c = min(max(x0 + 1, 0), 7);
    float v00 = seed[y0c * 8 + x0c], v01 = seed[y0c * 8 + x1c];
    float v10 = seed[y1c * 8 + x0c], v11 = seed[y1c * 8 + x1c];
    float top = v00 + wx * (v01 - v00);
    float bot = v10 + wx * (v11 - v10);
    return top + wy * (bot - top);
}

// ZERO-BARRIER kernel: each WAVE owns a 16x16 output tile with a private
// 24x24 double-buffered LDS slice and runs stage -> 4 shrinking-halo steps
// -> drain with no __syncthreads at all (same-wave LDS RAW ordered by
// lgkmcnt, pinned by an asm fence per step). 256 blocks x 9 waves = 9
// fully independent waves per CU — no lockstep, no barrier drain.
template <bool FIRST>
__global__ void __launch_bounds__(NT)
__attribute__((amdgpu_waves_per_eu(2, 4)))
fused_steps(
        const float* __restrict__ seed,
        const float* __restrict__ xin, float* __restrict__ xout,
        const float* __restrict__ gw1, const float* __restrict__ gb1,
        const float* __restrict__ gw2, const float* __restrict__ gb2) {
    __shared__ float lds[WPB][2][WI * WI];   // 9 x 2 x 576 x 4B = 41.5 KB
    const int wid = threadIdx.x >> 6;
    const int lane = threadIdx.x & 63;
    const int t = blockIdx.x * WPB + wid;    // 0..2303
    const int tiy = t / NWT, tix = t - tiy * NWT;
    const int gy0 = tiy * WT - KF, gx0 = tix * WT - KF;
    const bool border = (tix == 0) | (tix == NWT - 1) | (tiy == 0) | (tiy == NWT - 1);
    float (*buf)[WI * WI] = lds[wid];

    // ---- stage 24x24 wave tile: 9 px/lane exact (576 = 9*64) ----
#pragma unroll
    for (int i = 0; i < 9; ++i) {
        int p = lane + i * 64;
        int r = p / WI, c = p - r * WI;      // /24: compile-time magic mul
        int gy = gy0 + r, gx = gx0 + c;
        float v = 0.0f;
        if (gy >= 0 && gy < IMG && gx >= 0 && gx < IMG)
            v = FIRST ? bilinear8(seed, gy, gx) : xin[gy * IMG + gx];
        buf[0][p] = v;
    }

    const float b2v = gb2[0];

    // hoist biases into pinned VGPRs once (kills 16 per-px s->v movs)
    float vb[16];
#pragma unroll
    for (int ch = 0; ch < 16; ++ch) vb[ch] = gb1[ch];
    asm volatile("" : "+v"(vb[0]), "+v"(vb[1]), "+v"(vb[2]), "+v"(vb[3]),
                      "+v"(vb[4]), "+v"(vb[5]), "+v"(vb[6]), "+v"(vb[7]),
                      "+v"(vb[8]), "+v"(vb[9]), "+v"(vb[10]), "+v"(vb[11]),
                      "+v"(vb[12]), "+v"(vb[13]), "+v"(vb[14]), "+v"(vb[15]));

#pragma unroll
    for (int j = 0; j < KF; ++j) {
        const int S = (WI - 2) - 2 * j;      // 22,20,18,16
        const int off = j + 1;
        const int total = S * S;             // 484,400,324,256
        const int iters = (total + 63) / 64; // 8,7,6,4 (compile-time)
        const float* __restrict__ src = &buf[j & 1][0];
        float* __restrict__ dst = &buf[(j & 1) ^ 1][0];

#pragma unroll 1
        for (int k = 0; k < iters; ++k) {
            int p = lane + k * 64;
            bool ok = p < total;
            if (!ok) p = total - 1;          // clamp: duplicate a valid pixel
            int q = p / S;                   // S compile-time -> magic mul
            int r = off + q, c = off + (p - q * S);
            const float* s0 = &src[(r - 1) * WI + (c - 1)];
            float n0 = s0[0],          n1 = s0[1],          n2 = s0[2];
            float n3 = s0[WI],         n4 = s0[WI + 1],     n5 = s0[WI + 2];
            float n6 = s0[2 * WI],     n7 = s0[2 * WI + 1], n8 = s0[2 * WI + 2];

            // phase 1: 16 independent conv chains (ILP=16)
            float h[16];
#pragma unroll
            for (int ch = 0; ch < 16; ++ch) {
                const float* wc = &gw1[ch * 9];   // uniform -> s_load
                float tt = fmaf(wc[0], n0, vb[ch]);
                tt = fmaf(wc[1], n1, tt);
                tt = fmaf(wc[2], n2, tt);
                tt = fmaf(wc[3], n3, tt);
                tt = fmaf(wc[4], n4, tt);
                tt = fmaf(wc[5], n5, tt);
                tt = fmaf(wc[6], n6, tt);
                tt = fmaf(wc[7], n7, tt);
                tt = fmaf(wc[8], n8, tt);
                h[ch] = tt;
            }
            // zero-cost fence: pin two-phase schedule (prevents the R6
            // serializing loop interchange)
            asm volatile("" : "+v"(h[0]), "+v"(h[1]), "+v"(h[2]), "+v"(h[3]),
                              "+v"(h[4]), "+v"(h[5]), "+v"(h[6]), "+v"(h[7]),
                              "+v"(h[8]), "+v"(h[9]), "+v"(h[10]), "+v"(h[11]),
                              "+v"(h[12]), "+v"(h[13]), "+v"(h[14]), "+v"(h[15]));

            // phase 2: 16 independent GELU + accumulate
            float y = b2v;
#pragma unroll
            for (int ch = 0; ch < 16; ++ch)
                y = fmaf(gw2[ch], gelu_fast(h[ch]), y);

            float v = fmaf(RES_SCALE, y, n4);
            if (border) {
                int gy = gy0 + r, gx = gx0 + c;
                bool inimg = (gy >= 0) & (gy < IMG) & (gx >= 0) & (gx < IMG);
                // ghost pixels outside image stay 0 every iteration
                if (!inimg) v = 0.0f;
            }
            if (ok) dst[r * WI + c] = v;
        }
        // wave-local step boundary: all LDS writes retired before next
        // step's reads; "memory" stops cross-step ds reordering. No
        // __syncthreads — the slice is wave-private.
        asm volatile("s_waitcnt lgkmcnt(0)" ::: "memory");
    }

    // ---- drain 16x16 (always fully in-image; KF even -> buf[0]) ----
#pragma unroll
    for (int i = 0; i < 4; ++i) {            // 256 = 4*64 exact
        int p = lane + i * 64;
        int r = p >> 4, c = p & 15;
        xout[(gy0 + KF + r) * IMG + (gx0 + KF + c)] =
            buf[0][(KF + r) * WI + (KF + c)];
    }
}

extern "C" void kernel_launch(void* const* d_in, const int* in_sizes, int n_in,
                              void* d_out, int out_size, void* d_ws, size_t ws_size,
                              hipStream_t stream) {
    const float* seed = (const float*)d_in[0];
    const float* w1   = (const float*)d_in[1];
    const float* b1   = (const float*)d_in[2];
    const float* w2   = (const float*)d_in[3];
    const float* b2   = (const float*)d_in[4];
    // d_in[5]/d_in[6] are rows/cols = 768/768 (fixed by setup_inputs)

    float* out = (float*)d_out;
    float* ws  = (float*)d_ws;   // second ping-pong buffer (2.36 MB)

    float* a = out;
    float* b = ws;
    // 16 launches; first fuses the bilinear resize; even count -> ends in d_out
    fused_steps<true><<<NBLK, NT, 0, stream>>>(seed, a, b, w1, b1, w2, b2);
    { float* t = a; a = b; b = t; }
    for (int it = KF; it < NITER; it += KF) {
        fused_steps<false><<<NBLK, NT, 0, stream>>>(seed, a, b, w1, b1, w2, b2);
        float* t = a; a = b; b = t;
    }
}